// Round 7
// baseline (471.783 us; speedup 1.0000x reference)
//
#include <hip/hip_runtime.h>
#include <hip/hip_bf16.h>

#define N_NODES 20000
#define N_EDGES 320000
#define HID 256

typedef __attribute__((ext_vector_type(8))) short bf16x8;   // 8 bf16 = 4 VGPRs (MFMA A/B frag)
typedef __attribute__((ext_vector_type(4))) float f32x4;    // MFMA C/D frag
typedef __attribute__((ext_vector_type(8))) unsigned short us8;  // 16B row chunk

__device__ __forceinline__ float bf2f(ushort u) {
  union { unsigned int i; float f; } v; v.i = ((unsigned int)u) << 16; return v.f;
}
__device__ __forceinline__ ushort f2bf(float f) {
  union { float f; unsigned int i; } v; v.f = f;
  unsigned int r = v.i + 0x7FFFu + ((v.i >> 16) & 1u);   // RNE
  return (ushort)(r >> 16);
}

// ---------------------------------------------------------------------------
// Runtime dtype detection. flags[0]=1 -> x/weights fp32 (else bf16).
// flags[1]=1 -> edges int64 (else int32).
// ---------------------------------------------------------------------------
__global__ void detect_kernel(const void* x1, const void* ei1, int* flags) {
  __shared__ int cnt_wild, cnt_oddnz;
  if (threadIdx.x == 0) { cnt_wild = 0; cnt_oddnz = 0; }
  __syncthreads();
  const ushort* xu = (const ushort*)x1;
  int wild = 0;
#pragma unroll
  for (int k = 0; k < 4; k++) {
    ushort u = xu[threadIdx.x * 4 + k];
    int ex = (u >> 7) & 0xFF;
    if (ex >= 0x90) wild++;
  }
  if (wild) atomicAdd(&cnt_wild, wild);
  const int* ii = (const int*)ei1;
  if (ii[threadIdx.x * 2 + 1] != 0) atomicAdd(&cnt_oddnz, 1);
  __syncthreads();
  if (threadIdx.x == 0) {
    flags[0] = (cnt_wild > 64) ? 1 : 0;
    flags[1] = (cnt_oddnz < 8) ? 1 : 0;
  }
}

// Zero accumulated state (ws is poisoned 0xAA before every timed call).
__global__ void init_kernel(int* cnt0, int* cnt1, float* t0, float* t1) {
  int i = blockIdx.x * blockDim.x + threadIdx.x;
  if (i < N_NODES) { cnt0[i] = 0; cnt1[i] = 0; t0[i] = 0.f; t1[i] = 0.f; }
}

// Canonicalize edge_index -> int32 AND fused dst-histogram with rank capture
// (measured r2/r3: 640K device atomics ~= 40 us; replication is worse, r4).
__global__ void cvt_ei_count_kernel(const void* e0, const void* e1,
                                    int* o0, int* o1,
                                    int* cnt0, int* cnt1,
                                    int* rank0, int* rank1, const int* flags) {
  int b = blockIdx.y;
  const void* e = b ? e1 : e0;
  int* o = b ? o1 : o0;
  int* cnt = b ? cnt1 : cnt0;
  int* rank = b ? rank1 : rank0;
  int i = blockIdx.x * 256 + threadIdx.x;
  if (i >= 2 * N_EDGES) return;
  int v = flags[1] ? (int)((const long long*)e)[i] : ((const int*)e)[i];
  o[i] = v;
  if (i >= N_EDGES) rank[i - N_EDGES] = atomicAdd(&cnt[v], 1);
}

// Canonicalize x -> bf16. 4 elems/thread, vectorized both paths.
__global__ void cvt_x_kernel(const void* x0, const void* x1v,
                             ushort* o0, ushort* o1, const int* flags) {
  const void* x = blockIdx.y ? x1v : x0;
  ushort* o = blockIdx.y ? o1 : o0;
  int i4 = (blockIdx.x * 256 + threadIdx.x) * 4;
  if (i4 >= N_NODES * HID) return;
  if (flags[0]) {
    float4 v = *(const float4*)((const float*)x + i4);
    ushort4 w; w.x = f2bf(v.x); w.y = f2bf(v.y); w.z = f2bf(v.z); w.w = f2bf(v.w);
    *(ushort4*)(o + i4) = w;
  } else {
    *(ushort4*)(o + i4) = *(const ushort4*)((const ushort*)x + i4);
  }
}

// Canonicalize all weights/biases -> one packed bf16 buffer.
// W1/W2 stored TRANSPOSED (Wt[n*256+k]) -- kills gemm B-stage LDS conflicts (r5->r6).
// Layout: W1t[0] W2t[65536] W3[131072] Wl[196608] b1[197888] b2[198144]
//         b3[198400] bl[198656]; total 198661 elems.
__global__ void cvt_w_kernel(const void* W1, const void* W2, const void* W3, const void* Wl,
                             const void* b1, const void* b2, const void* b3, const void* bl,
                             ushort* out, const int* flags) {
  int i = blockIdx.x * 256 + threadIdx.x;
  if (i >= 198661) return;
  const void* src; int off; bool tr = false;
  if (i < 65536)       { src = W1; off = 0; tr = true; }
  else if (i < 131072) { src = W2; off = 65536; tr = true; }
  else if (i < 196608) { src = W3; off = 131072; }
  else if (i < 197888) { src = Wl; off = 196608; }
  else if (i < 198144) { src = b1; off = 197888; }
  else if (i < 198400) { src = b2; off = 198144; }
  else if (i < 198656) { src = b3; off = 198400; }
  else                 { src = bl; off = 198656; }
  int j = i - off;
  if (tr) j = (j & 255) * 256 + (j >> 8);   // read W[k][n] for out index (n,k)
  out[i] = flags[0] ? f2bf(((const float*)src)[j]) : ((const ushort*)src)[j];
}

// Exclusive scan -> CSR row_ptr, fused with dinv = rsqrt(cnt+1).
__global__ __launch_bounds__(1024) void scan_kernel(const int* cnt0, const int* cnt1,
                                                    int* rp0, int* rp1,
                                                    float* dinv0, float* dinv1) {
  const int* cnt = blockIdx.x ? cnt1 : cnt0;
  int* rp = blockIdx.x ? rp1 : rp0;
  float* dinv = blockIdx.x ? dinv1 : dinv0;
  __shared__ int sd[1024];
  int tid = threadIdx.x;
  int base = tid * 20;
  int pref[20];
  int run = 0;
#pragma unroll
  for (int k = 0; k < 20; k++) {
    int i = base + k;
    int c = (i < N_NODES) ? cnt[i] : 0;
    if (i < N_NODES) dinv[i] = rsqrtf((float)c + 1.0f);
    run += c;
    pref[k] = run;
  }
  sd[tid] = run;
  __syncthreads();
  for (int off = 1; off < 1024; off <<= 1) {
    int v = (tid >= off) ? sd[tid - off] : 0;
    __syncthreads();
    sd[tid] += v;
    __syncthreads();
  }
  int offset = sd[tid] - run;
  if (tid == 0) rp[0] = 0;
#pragma unroll
  for (int k = 0; k < 20; k++) {
    int i = base + k;
    if (i < N_NODES) rp[i + 1] = offset + pref[k];
  }
}

// Fill CSR (packed (src,coef) int2) using precomputed rank (no slot atomic),
// plus t[src] += dinv[dst] (feeds layer-3 shortcut c_j = dinv_j*(t_j+dinv_j)).
__global__ void fill_kernel(const int* ei0, const int* ei1,
                            const float* dinv0, const float* dinv1,
                            const int* rp0, const int* rp1,
                            const int* rank0, const int* rank1,
                            int2* eg0, int2* eg1,
                            float* t0, float* t1) {
  int e = blockIdx.x * blockDim.x + threadIdx.x;
  if (e >= N_EDGES) return;
  int b = blockIdx.y;
  const int* ei = b ? ei1 : ei0;
  const float* dinv = b ? dinv1 : dinv0;
  const int* rp = b ? rp1 : rp0;
  const int* rank = b ? rank1 : rank0;
  int2* eg = b ? eg1 : eg0;
  float* t = b ? t1 : t0;
  int src = ei[e], dst = ei[N_EDGES + e];
  int slot = rp[dst] + rank[e];
  float dd = dinv[dst];
  eg[slot] = make_int2(src, __float_as_int(dinv[src] * dd));
  atomicAdd(&t[src], dd);
}

// C[M,256] = A[M,256] @ W[256,256] with W given TRANSPOSED (Wt[n][k]).
// Block 256 thr = 4 waves; 64x64 tile; BK=32; 16x16x32 bf16 MFMA.
__global__ __launch_bounds__(256) void gemm_kernel(
    const ushort* __restrict__ A0, const ushort* __restrict__ A1,
    const ushort* __restrict__ Wt,
    ushort* __restrict__ C0, ushort* __restrict__ C1) {
  const ushort* A = blockIdx.z ? A1 : A0;
  ushort* C = blockIdx.z ? C1 : C0;
  int m0 = blockIdx.x * 64;
  int n0 = blockIdx.y * 64;
  __shared__ ushort As[64][40];   // row stride 80 B (not pow2 -> <=2-way, free)
  __shared__ ushort Bs[64][40];   // Bs[n][k] = Wt[(n0+n)*256 + k0+k]
  int tid = threadIdx.x;
  int wave = tid >> 6, lane = tid & 63;
  int quad = lane >> 4, r16 = lane & 15;
  f32x4 acc0 = {0.f, 0.f, 0.f, 0.f}, acc1 = acc0, acc2 = acc0, acc3 = acc0;
  int l_row = tid >> 2;           // 0..63
  int l_off = (tid & 3) * 8;      // 0,8,16,24
  for (int k0 = 0; k0 < 256; k0 += 32) {
    int gr = m0 + l_row;
    int4 va = {0, 0, 0, 0};
    if (gr < N_NODES) va = *(const int4*)(A + gr * 256 + k0 + l_off);
    *(int4*)&As[l_row][l_off] = va;
    int4 vb = *(const int4*)(Wt + (n0 + l_row) * 256 + k0 + l_off);
    *(int4*)&Bs[l_row][l_off] = vb;
    __syncthreads();
    bf16x8 a  = *(const bf16x8*)&As[wave * 16 + r16][quad * 8];
    bf16x8 b0 = *(const bf16x8*)&Bs[r16][quad * 8];
    bf16x8 b1 = *(const bf16x8*)&Bs[16 + r16][quad * 8];
    bf16x8 b2 = *(const bf16x8*)&Bs[32 + r16][quad * 8];
    bf16x8 b3 = *(const bf16x8*)&Bs[48 + r16][quad * 8];
    acc0 = __builtin_amdgcn_mfma_f32_16x16x32_bf16(a, b0, acc0, 0, 0, 0);
    acc1 = __builtin_amdgcn_mfma_f32_16x16x32_bf16(a, b1, acc1, 0, 0, 0);
    acc2 = __builtin_amdgcn_mfma_f32_16x16x32_bf16(a, b2, acc2, 0, 0, 0);
    acc3 = __builtin_amdgcn_mfma_f32_16x16x32_bf16(a, b3, acc3, 0, 0, 0);
    __syncthreads();
  }
  int orow = m0 + wave * 16 + quad * 4;
#pragma unroll
  for (int r = 0; r < 4; r++) {
    int gr = orow + r;
    if (gr < N_NODES) {
      ushort* cp = C + gr * 256 + n0 + r16;
      cp[0]  = f2bf(acc0[r]);
      cp[16] = f2bf(acc1[r]);
      cp[32] = f2bf(acc2[r]);
      cp[48] = f2bf(acc3[r]);
    }
  }
}

// XCD-sharded aggregation: H[i] = relu(dinv_i^2*XW[i] + sum_e coef_e*XW[col_e] + b).
// Shard = (branch, feature-quarter): 8 shards ~ 8 XCDs via blockIdx.x % 8
// round-robin; each shard's gather slice = 20000 x 128B = 2.56MB < 4MB L2/XCD,
// so steady-state gathers are L2 hits (r5/r6 FETCH showed ~75% L2 miss with
// the unsharded 20MB working set). Wave = 8 lane-groups x 8 lanes: group owns
// an edge, lane owns 8 features (16B b128); x2 unroll => 16 edges in flight.
// 3 shfl_xor steps merge groups; eg stream read non-temporally (don't evict
// the resident slice).
__global__ __launch_bounds__(256) void agg_kernel(
    const ushort* __restrict__ XW0, const ushort* __restrict__ XW1,
    const float* __restrict__ dinv0, const float* __restrict__ dinv1,
    const int* __restrict__ rp0, const int* __restrict__ rp1,
    const int2* __restrict__ eg0, const int2* __restrict__ eg1,
    const ushort* __restrict__ bias,
    ushort* __restrict__ H0, ushort* __restrict__ H1) {
  int shard = blockIdx.x & 7;             // -> XCD (round-robin heuristic)
  int nodeblk = blockIdx.x >> 3;          // 0..4999
  int branch = shard >> 2;
  int quarter = shard & 3;
  const ushort* XW = branch ? XW1 : XW0;
  const float* dinv = branch ? dinv1 : dinv0;
  const int* rp = branch ? rp1 : rp0;
  const int2* eg = branch ? eg1 : eg0;
  ushort* H = branch ? H1 : H0;
  int wave = threadIdx.x >> 6, lane = threadIdx.x & 63;
  int egrp = lane >> 3;                   // lane-group 0..7 = edge slot
  int j = lane & 7;                       // feature octet within quarter
  int fb = quarter * 64 + j * 8;          // feature base (16B aligned)
  int i = nodeblk * 4 + wave;             // node (20000 = 5000*4 exact)
  float accA[8], accB[8];
  if (egrp == 0) {                        // self-loop term lives in group 0
    float di = dinv[i];
    float selfw = di * di;
    us8 v = *(const us8*)(XW + i * 256 + fb);
#pragma unroll
    for (int k = 0; k < 8; k++) { accA[k] = selfw * bf2f(v[k]); accB[k] = 0.f; }
  } else {
#pragma unroll
    for (int k = 0; k < 8; k++) { accA[k] = 0.f; accB[k] = 0.f; }
  }
  int e0 = rp[i], e1 = rp[i + 1];
  int e = e0 + egrp;
  for (; e + 8 < e1; e += 16) {           // x2 unroll: 16 edges in flight/wave
    unsigned long long p0 = __builtin_nontemporal_load((const unsigned long long*)(eg + e));
    unsigned long long p1 = __builtin_nontemporal_load((const unsigned long long*)(eg + e + 8));
    int s0 = (int)(unsigned)p0, s1 = (int)(unsigned)p1;
    float w0 = __int_as_float((int)(p0 >> 32));
    float w1 = __int_as_float((int)(p1 >> 32));
    us8 r0 = *(const us8*)(XW + s0 * 256 + fb);
    us8 r1 = *(const us8*)(XW + s1 * 256 + fb);
#pragma unroll
    for (int k = 0; k < 8; k++) {
      accA[k] += w0 * bf2f(r0[k]);
      accB[k] += w1 * bf2f(r1[k]);
    }
  }
  if (e < e1) {
    unsigned long long p0 = __builtin_nontemporal_load((const unsigned long long*)(eg + e));
    int s0 = (int)(unsigned)p0;
    float w0 = __int_as_float((int)(p0 >> 32));
    us8 r0 = *(const us8*)(XW + s0 * 256 + fb);
#pragma unroll
    for (int k = 0; k < 8; k++) accA[k] += w0 * bf2f(r0[k]);
  }
  us8 bb = *(const us8*)(bias + fb);
  us8 o;
#pragma unroll
  for (int k = 0; k < 8; k++) {
    float s = accA[k] + accB[k];
    s += __shfl_xor(s, 8);                // merge 8 lane-groups
    s += __shfl_xor(s, 16);
    s += __shfl_xor(s, 32);
    o[k] = f2bf(fmaxf(s + bf2f(bb[k]), 0.f));
  }
  if (egrp == 0) *(us8*)(H + i * 256 + fb) = o;   // 8 lanes x 16B = 128B
}

// Partial column sums: wave w of block handles rows j = (blk*4+w) + 256*k.
__global__ __launch_bounds__(256) void colsum_kernel(
    const ushort* __restrict__ H0, const ushort* __restrict__ H1,
    const float* __restrict__ dinv0, const float* __restrict__ dinv1,
    const float* __restrict__ t0, const float* __restrict__ t1,
    float* __restrict__ P) {
  int b = blockIdx.y;
  const ushort* H = b ? H1 : H0;
  const float* dinv = b ? dinv1 : dinv0;
  const float* t = b ? t1 : t0;
  int wave = threadIdx.x >> 6, lane = threadIdx.x & 63;
  int wid = blockIdx.x * 4 + wave;        // 0..255
  int f4 = lane * 4;
  float a0 = 0.f, a1 = 0.f, a2 = 0.f, a3 = 0.f;
  for (int j = wid; j < N_NODES; j += 256) {
    float dj = dinv[j];
    float c = dj * (t[j] + dj);
    ushort4 u = *(const ushort4*)(H + j * 256 + f4);
    a0 += c * bf2f(u.x); a1 += c * bf2f(u.y);
    a2 += c * bf2f(u.z); a3 += c * bf2f(u.w);
  }
  __shared__ float part[4][256];
  part[wave][f4 + 0] = a0; part[wave][f4 + 1] = a1;
  part[wave][f4 + 2] = a2; part[wave][f4 + 3] = a3;
  __syncthreads();
  int f = threadIdx.x;
  float ssum = part[0][f] + part[1][f] + part[2][f] + part[3][f];
  P[(b * 64 + blockIdx.x) * 256 + f] = ssum;
}

// s = reduce partials; pooled = ((s0+s1)@W3)/(2N)+b3 ; out = pooled@Wl + bl
__global__ __launch_bounds__(256) void final_kernel(
    const float* __restrict__ P,
    const ushort* __restrict__ W3, const ushort* __restrict__ b3,
    const ushort* __restrict__ Wl, const ushort* __restrict__ bl,
    void* __restrict__ out, const int* __restrict__ flags) {
  __shared__ float v[256];
  __shared__ float pooled[256];
  int t = threadIdx.x;
  float acc0 = 0.f, acc1 = 0.f;
  for (int b = 0; b < 64; b++) {
    acc0 += P[b * 256 + t];
    acc1 += P[(64 + b) * 256 + t];
  }
  v[t] = acc0 + acc1;
  __syncthreads();
  float acc = 0.f;
  for (int f = 0; f < 256; f++) acc += v[f] * bf2f(W3[f * 256 + t]);
  pooled[t] = acc * (1.0f / (2.0f * N_NODES)) + bf2f(b3[t]);
  __syncthreads();
  if (t < 5) {
    float o = bf2f(bl[t]);
    for (int h = 0; h < 256; h++) o += pooled[h] * bf2f(Wl[h * 5 + t]);
    if (flags[0]) ((float*)out)[t] = o;
    else ((ushort*)out)[t] = f2bf(o);
  }
}

extern "C" void kernel_launch(void* const* d_in, const int* in_sizes, int n_in,
                              void* d_out, int out_size, void* d_ws, size_t ws_size,
                              hipStream_t stream) {
  const void* x1 = d_in[0];
  const void* ei1 = d_in[1];
  const void* x2 = d_in[2];
  const void* ei2 = d_in[3];
  const void* W1 = d_in[4];
  const void* b1 = d_in[5];
  const void* W2 = d_in[6];
  const void* b2 = d_in[7];
  const void* W3 = d_in[8];
  const void* b3 = d_in[9];
  const void* Wl = d_in[10];
  const void* bl = d_in[11];

  char* p = (char*)d_ws;
  auto alloc = [&](size_t bytes) {
    char* r = p;
    p += (bytes + 255) & ~size_t(255);
    return r;
  };
  int* flags   = (int*)alloc(256);
  float* dinv0 = (float*)alloc(N_NODES * 4);
  float* dinv1 = (float*)alloc(N_NODES * 4);
  float* t0    = (float*)alloc(N_NODES * 4);
  float* t1    = (float*)alloc(N_NODES * 4);
  int* cnt0    = (int*)alloc(N_NODES * 4);
  int* cnt1    = (int*)alloc(N_NODES * 4);
  int* rp0     = (int*)alloc((N_NODES + 1) * 4);
  int* rp1     = (int*)alloc((N_NODES + 1) * 4);
  int2* eg0    = (int2*)alloc((size_t)N_EDGES * 8);
  int2* eg1    = (int2*)alloc((size_t)N_EDGES * 8);
  float* Pp    = (float*)alloc(2 * 64 * 256 * 4);
  ushort* wbuf = (ushort*)alloc(198661 * 2);
  ushort* xw0  = (ushort*)alloc((size_t)N_NODES * HID * 2);
  ushort* xw1  = (ushort*)alloc((size_t)N_NODES * HID * 2);
  ushort* xc0  = (ushort*)alloc((size_t)N_NODES * HID * 2);
  ushort* xc1  = (ushort*)alloc((size_t)N_NODES * HID * 2);
  // Lifetime aliasing: ei32+rank live only until fill_kernel; xw0 is first
  // written by gemm1 (after fill). 2*2.56 + 2*1.28 = 7.7MB <= 10.24MB.
  int* ei32_0 = (int*)xw0;
  int* ei32_1 = ei32_0 + 2 * N_EDGES;
  int* rank0  = ei32_1 + 2 * N_EDGES;
  int* rank1  = rank0 + N_EDGES;
  // xc dead after gemm1 reads it; h first written by agg1 (after gemm1).
  ushort* h0 = xc0;
  ushort* h1 = xc1;

  ushort* Wc1 = wbuf + 0;        // transposed
  ushort* Wc2 = wbuf + 65536;    // transposed
  ushort* Wc3 = wbuf + 131072;
  ushort* Wlc = wbuf + 196608;
  ushort* bc1 = wbuf + 197888;
  ushort* bc2 = wbuf + 198144;
  ushort* bc3 = wbuf + 198400;
  ushort* blc = wbuf + 198656;

  // --- dtype detection + canonicalization + graph prep ---
  detect_kernel<<<1, 256, 0, stream>>>(x1, ei1, flags);
  init_kernel<<<(N_NODES + 255) / 256, 256, 0, stream>>>(cnt0, cnt1, t0, t1);
  cvt_ei_count_kernel<<<dim3((2 * N_EDGES + 255) / 256, 2), 256, 0, stream>>>(
      ei1, ei2, ei32_0, ei32_1, cnt0, cnt1, rank0, rank1, flags);
  cvt_x_kernel<<<dim3(N_NODES * HID / 1024, 2), 256, 0, stream>>>(
      x1, x2, xc0, xc1, flags);
  cvt_w_kernel<<<(198661 + 255) / 256, 256, 0, stream>>>(
      W1, W2, W3, Wl, b1, b2, b3, bl, wbuf, flags);
  scan_kernel<<<2, 1024, 0, stream>>>(cnt0, cnt1, rp0, rp1, dinv0, dinv1);
  fill_kernel<<<dim3((N_EDGES + 255) / 256, 2), 256, 0, stream>>>(
      ei32_0, ei32_1, dinv0, dinv1, rp0, rp1, rank0, rank1, eg0, eg1, t0, t1);

  // Layer 1: xw = x @ W1 ; h = relu(agg(xw) + b1)
  gemm_kernel<<<dim3(313, 4, 2), 256, 0, stream>>>(xc0, xc1, Wc1, xw0, xw1);
  agg_kernel<<<dim3(5000 * 8), 256, 0, stream>>>(
      xw0, xw1, dinv0, dinv1, rp0, rp1, eg0, eg1, bc1, h0, h1);

  // Layer 2: xw = h @ W2 ; h = relu(agg(xw) + b2)
  gemm_kernel<<<dim3(313, 4, 2), 256, 0, stream>>>(h0, h1, Wc2, xw0, xw1);
  agg_kernel<<<dim3(5000 * 8), 256, 0, stream>>>(
      xw0, xw1, dinv0, dinv1, rp0, rp1, eg0, eg1, bc2, h0, h1);

  // Layer 3 + pool collapsed: s = sum_j c_j h2_j ; out = ((s0+s1)W3/(2N)+b3)@Wl+bl
  colsum_kernel<<<dim3(64, 2), 256, 0, stream>>>(h0, h1, dinv0, dinv1, t0, t1, Pp);
  final_kernel<<<1, 256, 0, stream>>>(Pp, Wc3, bc3, Wlc, blc, d_out, flags);
}

// Round 8
// 430.719 us; speedup vs baseline: 1.0953x; 1.0953x over previous
//
#include <hip/hip_runtime.h>
#include <hip/hip_bf16.h>

#define N_NODES 20000
#define N_EDGES 320000
#define HID 256

typedef __attribute__((ext_vector_type(8))) short bf16x8;   // 8 bf16 = 4 VGPRs (MFMA A/B frag)
typedef __attribute__((ext_vector_type(4))) float f32x4;    // MFMA C/D frag
typedef __attribute__((ext_vector_type(8))) unsigned short us8;  // 16B row chunk

__device__ __forceinline__ float bf2f(ushort u) {
  union { unsigned int i; float f; } v; v.i = ((unsigned int)u) << 16; return v.f;
}
__device__ __forceinline__ ushort f2bf(float f) {
  union { float f; unsigned int i; } v; v.f = f;
  unsigned int r = v.i + 0x7FFFu + ((v.i >> 16) & 1u);   // RNE
  return (ushort)(r >> 16);
}

// ---------------------------------------------------------------------------
// init (zero accumulated state) + runtime dtype detection fused.
// flags[0]=1 -> x/weights fp32 (else bf16). flags[1]=1 -> edges int64.
// Last block does detection; others zero cnt/t.
// ---------------------------------------------------------------------------
__global__ void init_detect_kernel(int* cnt0, int* cnt1, float* t0, float* t1,
                                   const void* x1, const void* ei1, int* flags) {
  if (blockIdx.x == gridDim.x - 1) {
    __shared__ int cnt_wild, cnt_oddnz;
    if (threadIdx.x == 0) { cnt_wild = 0; cnt_oddnz = 0; }
    __syncthreads();
    const ushort* xu = (const ushort*)x1;
    int wild = 0;
#pragma unroll
    for (int k = 0; k < 4; k++) {
      ushort u = xu[threadIdx.x * 4 + k];
      int ex = (u >> 7) & 0xFF;
      if (ex >= 0x90) wild++;
    }
    if (wild) atomicAdd(&cnt_wild, wild);
    const int* ii = (const int*)ei1;
    if (ii[threadIdx.x * 2 + 1] != 0) atomicAdd(&cnt_oddnz, 1);
    __syncthreads();
    if (threadIdx.x == 0) {
      flags[0] = (cnt_wild > 64) ? 1 : 0;
      flags[1] = (cnt_oddnz < 8) ? 1 : 0;
    }
    return;
  }
  int i = blockIdx.x * blockDim.x + threadIdx.x;
  if (i < N_NODES) { cnt0[i] = 0; cnt1[i] = 0; t0[i] = 0.f; t1[i] = 0.f; }
}

// Canonicalize edge_index -> int32 AND fused dst-histogram with rank capture
// (measured r2/r3: 640K device atomics ~= 40 us; replication is worse, r4).
__global__ void cvt_ei_count_kernel(const void* e0, const void* e1,
                                    int* o0, int* o1,
                                    int* cnt0, int* cnt1,
                                    int* rank0, int* rank1, const int* flags) {
  int b = blockIdx.y;
  const void* e = b ? e1 : e0;
  int* o = b ? o1 : o0;
  int* cnt = b ? cnt1 : cnt0;
  int* rank = b ? rank1 : rank0;
  int i = blockIdx.x * 256 + threadIdx.x;
  if (i >= 2 * N_EDGES) return;
  int v = flags[1] ? (int)((const long long*)e)[i] : ((const int*)e)[i];
  o[i] = v;
  if (i >= N_EDGES) rank[i - N_EDGES] = atomicAdd(&cnt[v], 1);
}

// Canonicalize x -> bf16. 4 elems/thread, vectorized both paths.
__global__ void cvt_x_kernel(const void* x0, const void* x1v,
                             ushort* o0, ushort* o1, const int* flags) {
  const void* x = blockIdx.y ? x1v : x0;
  ushort* o = blockIdx.y ? o1 : o0;
  int i4 = (blockIdx.x * 256 + threadIdx.x) * 4;
  if (i4 >= N_NODES * HID) return;
  if (flags[0]) {
    float4 v = *(const float4*)((const float*)x + i4);
    ushort4 w; w.x = f2bf(v.x); w.y = f2bf(v.y); w.z = f2bf(v.z); w.w = f2bf(v.w);
    *(ushort4*)(o + i4) = w;
  } else {
    *(ushort4*)(o + i4) = *(const ushort4*)((const ushort*)x + i4);
  }
}

// Canonicalize all weights/biases -> one packed bf16 buffer.
// W1/W2 stored TRANSPOSED (Wt[n*256+k]) -- kills gemm B-stage LDS conflicts (r5->r6).
// Layout: W1t[0] W2t[65536] W3[131072] Wl[196608] b1[197888] b2[198144]
//         b3[198400] bl[198656]; total 198661 elems.
__global__ void cvt_w_kernel(const void* W1, const void* W2, const void* W3, const void* Wl,
                             const void* b1, const void* b2, const void* b3, const void* bl,
                             ushort* out, const int* flags) {
  int i = blockIdx.x * 256 + threadIdx.x;
  if (i >= 198661) return;
  const void* src; int off; bool tr = false;
  if (i < 65536)       { src = W1; off = 0; tr = true; }
  else if (i < 131072) { src = W2; off = 65536; tr = true; }
  else if (i < 196608) { src = W3; off = 131072; }
  else if (i < 197888) { src = Wl; off = 196608; }
  else if (i < 198144) { src = b1; off = 197888; }
  else if (i < 198400) { src = b2; off = 198144; }
  else if (i < 198656) { src = b3; off = 198400; }
  else                 { src = bl; off = 198656; }
  int j = i - off;
  if (tr) j = (j & 255) * 256 + (j >> 8);   // read W[k][n] for out index (n,k)
  out[i] = flags[0] ? f2bf(((const float*)src)[j]) : ((const ushort*)src)[j];
}

// Exclusive scan -> CSR row_ptr, fused with dinv = rsqrt(cnt+1).
__global__ __launch_bounds__(1024) void scan_kernel(const int* cnt0, const int* cnt1,
                                                    int* rp0, int* rp1,
                                                    float* dinv0, float* dinv1) {
  const int* cnt = blockIdx.x ? cnt1 : cnt0;
  int* rp = blockIdx.x ? rp1 : rp0;
  float* dinv = blockIdx.x ? dinv1 : dinv0;
  __shared__ int sd[1024];
  int tid = threadIdx.x;
  int base = tid * 20;
  int pref[20];
  int run = 0;
#pragma unroll
  for (int k = 0; k < 20; k++) {
    int i = base + k;
    int c = (i < N_NODES) ? cnt[i] : 0;
    if (i < N_NODES) dinv[i] = rsqrtf((float)c + 1.0f);
    run += c;
    pref[k] = run;
  }
  sd[tid] = run;
  __syncthreads();
  for (int off = 1; off < 1024; off <<= 1) {
    int v = (tid >= off) ? sd[tid - off] : 0;
    __syncthreads();
    sd[tid] += v;
    __syncthreads();
  }
  int offset = sd[tid] - run;
  if (tid == 0) rp[0] = 0;
#pragma unroll
  for (int k = 0; k < 20; k++) {
    int i = base + k;
    if (i < N_NODES) rp[i + 1] = offset + pref[k];
  }
}

// Fill CSR (packed (src,coef) int2) using precomputed rank (no slot atomic),
// plus t[src] += dinv[dst] (feeds layer-3 shortcut c_j = dinv_j*(t_j+dinv_j)).
__global__ void fill_kernel(const int* ei0, const int* ei1,
                            const float* dinv0, const float* dinv1,
                            const int* rp0, const int* rp1,
                            const int* rank0, const int* rank1,
                            int2* eg0, int2* eg1,
                            float* t0, float* t1) {
  int e = blockIdx.x * blockDim.x + threadIdx.x;
  if (e >= N_EDGES) return;
  int b = blockIdx.y;
  const int* ei = b ? ei1 : ei0;
  const float* dinv = b ? dinv1 : dinv0;
  const int* rp = b ? rp1 : rp0;
  const int* rank = b ? rank1 : rank0;
  int2* eg = b ? eg1 : eg0;
  float* t = b ? t1 : t0;
  int src = ei[e], dst = ei[N_EDGES + e];
  int slot = rp[dst] + rank[e];
  float dd = dinv[dst];
  eg[slot] = make_int2(src, __float_as_int(dinv[src] * dd));
  atomicAdd(&t[src], dd);
}

// C[M,256] = A[M,256] @ W[256,256] with W given TRANSPOSED (Wt[n][k]).
// Block 256 thr = 4 waves; 64x64 tile; BK=32; 16x16x32 bf16 MFMA.
__global__ __launch_bounds__(256) void gemm_kernel(
    const ushort* __restrict__ A0, const ushort* __restrict__ A1,
    const ushort* __restrict__ Wt,
    ushort* __restrict__ C0, ushort* __restrict__ C1) {
  const ushort* A = blockIdx.z ? A1 : A0;
  ushort* C = blockIdx.z ? C1 : C0;
  int m0 = blockIdx.x * 64;
  int n0 = blockIdx.y * 64;
  __shared__ ushort As[64][40];   // row stride 80 B (not pow2 -> <=2-way, free)
  __shared__ ushort Bs[64][40];   // Bs[n][k] = Wt[(n0+n)*256 + k0+k]
  int tid = threadIdx.x;
  int wave = tid >> 6, lane = tid & 63;
  int quad = lane >> 4, r16 = lane & 15;
  f32x4 acc0 = {0.f, 0.f, 0.f, 0.f}, acc1 = acc0, acc2 = acc0, acc3 = acc0;
  int l_row = tid >> 2;           // 0..63
  int l_off = (tid & 3) * 8;      // 0,8,16,24
  for (int k0 = 0; k0 < 256; k0 += 32) {
    int gr = m0 + l_row;
    int4 va = {0, 0, 0, 0};
    if (gr < N_NODES) va = *(const int4*)(A + gr * 256 + k0 + l_off);
    *(int4*)&As[l_row][l_off] = va;
    int4 vb = *(const int4*)(Wt + (n0 + l_row) * 256 + k0 + l_off);
    *(int4*)&Bs[l_row][l_off] = vb;
    __syncthreads();
    bf16x8 a  = *(const bf16x8*)&As[wave * 16 + r16][quad * 8];
    bf16x8 b0 = *(const bf16x8*)&Bs[r16][quad * 8];
    bf16x8 b1 = *(const bf16x8*)&Bs[16 + r16][quad * 8];
    bf16x8 b2 = *(const bf16x8*)&Bs[32 + r16][quad * 8];
    bf16x8 b3 = *(const bf16x8*)&Bs[48 + r16][quad * 8];
    acc0 = __builtin_amdgcn_mfma_f32_16x16x32_bf16(a, b0, acc0, 0, 0, 0);
    acc1 = __builtin_amdgcn_mfma_f32_16x16x32_bf16(a, b1, acc1, 0, 0, 0);
    acc2 = __builtin_amdgcn_mfma_f32_16x16x32_bf16(a, b2, acc2, 0, 0, 0);
    acc3 = __builtin_amdgcn_mfma_f32_16x16x32_bf16(a, b3, acc3, 0, 0, 0);
    __syncthreads();
  }
  int orow = m0 + wave * 16 + quad * 4;
#pragma unroll
  for (int r = 0; r < 4; r++) {
    int gr = orow + r;
    if (gr < N_NODES) {
      ushort* cp = C + gr * 256 + n0 + r16;
      cp[0]  = f2bf(acc0[r]);
      cp[16] = f2bf(acc1[r]);
      cp[32] = f2bf(acc2[r]);
      cp[48] = f2bf(acc3[r]);
    }
  }
}

// XCD-sharded aggregation, group-per-NODE (r8): wave = 8 lane-groups x 8
// lanes; each GROUP owns a node and serially walks its edge list; lane owns
// 8 features of the shard's 64-feature quarter. NO cross-lane merge (r7's
// 24-shfl epilogue eliminated); 8 nodes of output per wave (8x overhead
// amortization vs r7). Shard = (branch, quarter) -> blockIdx.x % 8 -> XCD;
// slice = 20000 x 128B = 2.56MB < 4MB L2 (r7 measured FETCH 120->21MB).
// x2 unroll: 16 independent gathers in flight/wave. Trip count = wave-uniform
// max degree over the 8 groups (E[max8 Po(16)] ~ 26, bounded divergence);
// inactive groups clamp to row 0 with weight 0 (branch-free).
__global__ __launch_bounds__(256) void agg_kernel(
    const ushort* __restrict__ XW0, const ushort* __restrict__ XW1,
    const float* __restrict__ dinv0, const float* __restrict__ dinv1,
    const int* __restrict__ rp0, const int* __restrict__ rp1,
    const int2* __restrict__ eg0, const int2* __restrict__ eg1,
    const ushort* __restrict__ bias,
    ushort* __restrict__ H0, ushort* __restrict__ H1) {
  int shard = blockIdx.x & 7;             // -> XCD (round-robin heuristic)
  int nodeblk = blockIdx.x >> 3;          // 0..624
  int branch = shard >> 2;
  int quarter = shard & 3;
  const ushort* XW = branch ? XW1 : XW0;
  const float* dinv = branch ? dinv1 : dinv0;
  const int* rp = branch ? rp1 : rp0;
  const int2* eg = branch ? eg1 : eg0;
  ushort* H = branch ? H1 : H0;
  int wave = threadIdx.x >> 6, lane = threadIdx.x & 63;
  int grp = lane >> 3;                    // 0..7: node slot within wave
  int j = lane & 7;                       // feature octet within quarter
  int fb = quarter * 64 + j * 8;          // feature base (16B aligned)
  int i = nodeblk * 32 + wave * 8 + grp;  // node: 625*32 = 20000 exact
  float di = dinv[i];
  float selfw = di * di;
  us8 v = *(const us8*)(XW + i * 256 + fb);
  float accA[8], accB[8];
#pragma unroll
  for (int k = 0; k < 8; k++) { accA[k] = selfw * bf2f(v[k]); accB[k] = 0.f; }
  int e = rp[i], eend = rp[i + 1];
  int m = eend - e;                       // degree (uniform within group)
  m = max(m, __shfl_xor(m, 8));           // wave-max over the 8 groups
  m = max(m, __shfl_xor(m, 16));
  m = max(m, __shfl_xor(m, 32));
  int trips = (m + 1) >> 1;
  for (int t = 0; t < trips; t++) {
    bool a0 = e < eend;
    bool a1 = e + 1 < eend;
    long long q0 = __builtin_nontemporal_load((const long long*)(eg + (a0 ? e : 0)));
    long long q1 = __builtin_nontemporal_load((const long long*)(eg + (a1 ? e + 1 : 0)));
    int s0 = (int)(unsigned)(unsigned long long)q0;
    int s1 = (int)(unsigned)(unsigned long long)q1;
    float w0 = a0 ? __int_as_float((int)(q0 >> 32)) : 0.f;
    float w1 = a1 ? __int_as_float((int)(q1 >> 32)) : 0.f;
    us8 r0 = *(const us8*)(XW + s0 * 256 + fb);
    us8 r1 = *(const us8*)(XW + s1 * 256 + fb);
#pragma unroll
    for (int k = 0; k < 8; k++) {
      accA[k] += w0 * bf2f(r0[k]);
      accB[k] += w1 * bf2f(r1[k]);
    }
    e += 2;
  }
  us8 bb = *(const us8*)(bias + fb);
  us8 o;
#pragma unroll
  for (int k = 0; k < 8; k++) {
    o[k] = f2bf(fmaxf(accA[k] + accB[k] + bf2f(bb[k]), 0.f));
  }
  *(us8*)(H + i * 256 + fb) = o;          // group writes its node's quarter
}

// Partial column sums: wave w of block handles rows j = (blk*4+w) + 256*k.
__global__ __launch_bounds__(256) void colsum_kernel(
    const ushort* __restrict__ H0, const ushort* __restrict__ H1,
    const float* __restrict__ dinv0, const float* __restrict__ dinv1,
    const float* __restrict__ t0, const float* __restrict__ t1,
    float* __restrict__ P) {
  int b = blockIdx.y;
  const ushort* H = b ? H1 : H0;
  const float* dinv = b ? dinv1 : dinv0;
  const float* t = b ? t1 : t0;
  int wave = threadIdx.x >> 6, lane = threadIdx.x & 63;
  int wid = blockIdx.x * 4 + wave;        // 0..255
  int f4 = lane * 4;
  float a0 = 0.f, a1 = 0.f, a2 = 0.f, a3 = 0.f;
  for (int j = wid; j < N_NODES; j += 256) {
    float dj = dinv[j];
    float c = dj * (t[j] + dj);
    ushort4 u = *(const ushort4*)(H + j * 256 + f4);
    a0 += c * bf2f(u.x); a1 += c * bf2f(u.y);
    a2 += c * bf2f(u.z); a3 += c * bf2f(u.w);
  }
  __shared__ float part[4][256];
  part[wave][f4 + 0] = a0; part[wave][f4 + 1] = a1;
  part[wave][f4 + 2] = a2; part[wave][f4 + 3] = a3;
  __syncthreads();
  int f = threadIdx.x;
  float ssum = part[0][f] + part[1][f] + part[2][f] + part[3][f];
  P[(b * 64 + blockIdx.x) * 256 + f] = ssum;
}

// s = reduce partials; pooled = ((s0+s1)@W3)/(2N)+b3 ; out = pooled@Wl + bl
__global__ __launch_bounds__(256) void final_kernel(
    const float* __restrict__ P,
    const ushort* __restrict__ W3, const ushort* __restrict__ b3,
    const ushort* __restrict__ Wl, const ushort* __restrict__ bl,
    void* __restrict__ out, const int* __restrict__ flags) {
  __shared__ float v[256];
  __shared__ float pooled[256];
  int t = threadIdx.x;
  float acc0 = 0.f, acc1 = 0.f;
  for (int b = 0; b < 64; b++) {
    acc0 += P[b * 256 + t];
    acc1 += P[(64 + b) * 256 + t];
  }
  v[t] = acc0 + acc1;
  __syncthreads();
  float acc = 0.f;
  for (int f = 0; f < 256; f++) acc += v[f] * bf2f(W3[f * 256 + t]);
  pooled[t] = acc * (1.0f / (2.0f * N_NODES)) + bf2f(b3[t]);
  __syncthreads();
  if (t < 5) {
    float o = bf2f(bl[t]);
    for (int h = 0; h < 256; h++) o += pooled[h] * bf2f(Wl[h * 5 + t]);
    if (flags[0]) ((float*)out)[t] = o;
    else ((ushort*)out)[t] = f2bf(o);
  }
}

extern "C" void kernel_launch(void* const* d_in, const int* in_sizes, int n_in,
                              void* d_out, int out_size, void* d_ws, size_t ws_size,
                              hipStream_t stream) {
  const void* x1 = d_in[0];
  const void* ei1 = d_in[1];
  const void* x2 = d_in[2];
  const void* ei2 = d_in[3];
  const void* W1 = d_in[4];
  const void* b1 = d_in[5];
  const void* W2 = d_in[6];
  const void* b2 = d_in[7];
  const void* W3 = d_in[8];
  const void* b3 = d_in[9];
  const void* Wl = d_in[10];
  const void* bl = d_in[11];

  char* p = (char*)d_ws;
  auto alloc = [&](size_t bytes) {
    char* r = p;
    p += (bytes + 255) & ~size_t(255);
    return r;
  };
  int* flags   = (int*)alloc(256);
  float* dinv0 = (float*)alloc(N_NODES * 4);
  float* dinv1 = (float*)alloc(N_NODES * 4);
  float* t0    = (float*)alloc(N_NODES * 4);
  float* t1    = (float*)alloc(N_NODES * 4);
  int* cnt0    = (int*)alloc(N_NODES * 4);
  int* cnt1    = (int*)alloc(N_NODES * 4);
  int* rp0     = (int*)alloc((N_NODES + 1) * 4);
  int* rp1     = (int*)alloc((N_NODES + 1) * 4);
  int2* eg0    = (int2*)alloc((size_t)N_EDGES * 8);
  int2* eg1    = (int2*)alloc((size_t)N_EDGES * 8);
  float* Pp    = (float*)alloc(2 * 64 * 256 * 4);
  ushort* wbuf = (ushort*)alloc(198661 * 2);
  ushort* xw0  = (ushort*)alloc((size_t)N_NODES * HID * 2);
  ushort* xw1  = (ushort*)alloc((size_t)N_NODES * HID * 2);
  ushort* xc0  = (ushort*)alloc((size_t)N_NODES * HID * 2);
  ushort* xc1  = (ushort*)alloc((size_t)N_NODES * HID * 2);
  // Lifetime aliasing: ei32+rank live only until fill_kernel; xw0 is first
  // written by gemm1 (after fill). 2*2.56 + 2*1.28 = 7.7MB <= 10.24MB.
  int* ei32_0 = (int*)xw0;
  int* ei32_1 = ei32_0 + 2 * N_EDGES;
  int* rank0  = ei32_1 + 2 * N_EDGES;
  int* rank1  = rank0 + N_EDGES;
  // xc dead after gemm1 reads it; h first written by agg1 (after gemm1).
  ushort* h0 = xc0;
  ushort* h1 = xc1;

  ushort* Wc1 = wbuf + 0;        // transposed
  ushort* Wc2 = wbuf + 65536;    // transposed
  ushort* Wc3 = wbuf + 131072;
  ushort* Wlc = wbuf + 196608;
  ushort* bc1 = wbuf + 197888;
  ushort* bc2 = wbuf + 198144;
  ushort* bc3 = wbuf + 198400;
  ushort* blc = wbuf + 198656;

  // --- init+detect fused, canonicalization, graph prep ---
  init_detect_kernel<<<(N_NODES + 255) / 256 + 1, 256, 0, stream>>>(
      cnt0, cnt1, t0, t1, x1, ei1, flags);
  cvt_ei_count_kernel<<<dim3((2 * N_EDGES + 255) / 256, 2), 256, 0, stream>>>(
      ei1, ei2, ei32_0, ei32_1, cnt0, cnt1, rank0, rank1, flags);
  cvt_x_kernel<<<dim3(N_NODES * HID / 1024, 2), 256, 0, stream>>>(
      x1, x2, xc0, xc1, flags);
  cvt_w_kernel<<<(198661 + 255) / 256, 256, 0, stream>>>(
      W1, W2, W3, Wl, b1, b2, b3, bl, wbuf, flags);
  scan_kernel<<<2, 1024, 0, stream>>>(cnt0, cnt1, rp0, rp1, dinv0, dinv1);
  fill_kernel<<<dim3((N_EDGES + 255) / 256, 2), 256, 0, stream>>>(
      ei32_0, ei32_1, dinv0, dinv1, rp0, rp1, rank0, rank1, eg0, eg1, t0, t1);

  // Layer 1: xw = x @ W1 ; h = relu(agg(xw) + b1)
  gemm_kernel<<<dim3(313, 4, 2), 256, 0, stream>>>(xc0, xc1, Wc1, xw0, xw1);
  agg_kernel<<<dim3(5000), 256, 0, stream>>>(
      xw0, xw1, dinv0, dinv1, rp0, rp1, eg0, eg1, bc1, h0, h1);

  // Layer 2: xw = h @ W2 ; h = relu(agg(xw) + b2)
  gemm_kernel<<<dim3(313, 4, 2), 256, 0, stream>>>(h0, h1, Wc2, xw0, xw1);
  agg_kernel<<<dim3(5000), 256, 0, stream>>>(
      xw0, xw1, dinv0, dinv1, rp0, rp1, eg0, eg1, bc2, h0, h1);

  // Layer 3 + pool collapsed: s = sum_j c_j h2_j ; out = ((s0+s1)W3/(2N)+b3)@Wl+bl
  colsum_kernel<<<dim3(64, 2), 256, 0, stream>>>(h0, h1, dinv0, dinv1, t0, t1, Pp);
  final_kernel<<<1, 256, 0, stream>>>(Pp, Wc3, bc3, Wlc, blc, d_out, flags);
}

// Round 9
// 381.248 us; speedup vs baseline: 1.2375x; 1.1298x over previous
//
#include <hip/hip_runtime.h>
#include <hip/hip_bf16.h>

#define N_NODES 20000
#define N_EDGES 320000
#define HID 256

typedef __attribute__((ext_vector_type(8))) short bf16x8;   // 8 bf16 = 4 VGPRs (MFMA A/B frag)
typedef __attribute__((ext_vector_type(4))) float f32x4;    // MFMA C/D frag
typedef __attribute__((ext_vector_type(8))) unsigned short us8;  // 16B row chunk

__device__ __forceinline__ float bf2f(ushort u) {
  union { unsigned int i; float f; } v; v.i = ((unsigned int)u) << 16; return v.f;
}
__device__ __forceinline__ ushort f2bf(float f) {
  union { float f; unsigned int i; } v; v.f = f;
  unsigned int r = v.i + 0x7FFFu + ((v.i >> 16) & 1u);   // RNE
  return (ushort)(r >> 16);
}

// ---------------------------------------------------------------------------
// init (zero accumulated state) + runtime dtype detection fused.
// flags[0]=1 -> x/weights fp32 (else bf16). flags[1]=1 -> edges int64.
// ---------------------------------------------------------------------------
__global__ void init_detect_kernel(int* cnt0, int* cnt1, float* t0, float* t1,
                                   const void* x1, const void* ei1, int* flags) {
  if (blockIdx.x == gridDim.x - 1) {
    __shared__ int cnt_wild, cnt_oddnz;
    if (threadIdx.x == 0) { cnt_wild = 0; cnt_oddnz = 0; }
    __syncthreads();
    const ushort* xu = (const ushort*)x1;
    int wild = 0;
#pragma unroll
    for (int k = 0; k < 4; k++) {
      ushort u = xu[threadIdx.x * 4 + k];
      int ex = (u >> 7) & 0xFF;
      if (ex >= 0x90) wild++;
    }
    if (wild) atomicAdd(&cnt_wild, wild);
    const int* ii = (const int*)ei1;
    if (ii[threadIdx.x * 2 + 1] != 0) atomicAdd(&cnt_oddnz, 1);
    __syncthreads();
    if (threadIdx.x == 0) {
      flags[0] = (cnt_wild > 64) ? 1 : 0;
      flags[1] = (cnt_oddnz < 8) ? 1 : 0;
    }
    return;
  }
  int i = blockIdx.x * blockDim.x + threadIdx.x;
  if (i < N_NODES) { cnt0[i] = 0; cnt1[i] = 0; t0[i] = 0.f; t1[i] = 0.f; }
}

// Canonicalize edge_index -> int32 AND fused dst-histogram with rank capture
// (measured r2/r3: 640K device atomics ~= 40 us; replication is worse, r4).
__global__ void cvt_ei_count_kernel(const void* e0, const void* e1,
                                    int* o0, int* o1,
                                    int* cnt0, int* cnt1,
                                    int* rank0, int* rank1, const int* flags) {
  int b = blockIdx.y;
  const void* e = b ? e1 : e0;
  int* o = b ? o1 : o0;
  int* cnt = b ? cnt1 : cnt0;
  int* rank = b ? rank1 : rank0;
  int i = blockIdx.x * 256 + threadIdx.x;
  if (i >= 2 * N_EDGES) return;
  int v = flags[1] ? (int)((const long long*)e)[i] : ((const int*)e)[i];
  o[i] = v;
  if (i >= N_EDGES) rank[i - N_EDGES] = atomicAdd(&cnt[v], 1);
}

// Canonicalize x -> bf16. 4 elems/thread, vectorized both paths.
__global__ void cvt_x_kernel(const void* x0, const void* x1v,
                             ushort* o0, ushort* o1, const int* flags) {
  const void* x = blockIdx.y ? x1v : x0;
  ushort* o = blockIdx.y ? o1 : o0;
  int i4 = (blockIdx.x * 256 + threadIdx.x) * 4;
  if (i4 >= N_NODES * HID) return;
  if (flags[0]) {
    float4 v = *(const float4*)((const float*)x + i4);
    ushort4 w; w.x = f2bf(v.x); w.y = f2bf(v.y); w.z = f2bf(v.z); w.w = f2bf(v.w);
    *(ushort4*)(o + i4) = w;
  } else {
    *(ushort4*)(o + i4) = *(const ushort4*)((const ushort*)x + i4);
  }
}

// Canonicalize all weights/biases -> one packed bf16 buffer.
// W1/W2 stored TRANSPOSED (Wt[n*256+k]) -- kills gemm B-stage LDS conflicts (r5->r6).
// Layout: W1t[0] W2t[65536] W3[131072] Wl[196608] b1[197888] b2[198144]
//         b3[198400] bl[198656]; total 198661 elems.
__global__ void cvt_w_kernel(const void* W1, const void* W2, const void* W3, const void* Wl,
                             const void* b1, const void* b2, const void* b3, const void* bl,
                             ushort* out, const int* flags) {
  int i = blockIdx.x * 256 + threadIdx.x;
  if (i >= 198661) return;
  const void* src; int off; bool tr = false;
  if (i < 65536)       { src = W1; off = 0; tr = true; }
  else if (i < 131072) { src = W2; off = 65536; tr = true; }
  else if (i < 196608) { src = W3; off = 131072; }
  else if (i < 197888) { src = Wl; off = 196608; }
  else if (i < 198144) { src = b1; off = 197888; }
  else if (i < 198400) { src = b2; off = 198144; }
  else if (i < 198656) { src = b3; off = 198400; }
  else                 { src = bl; off = 198656; }
  int j = i - off;
  if (tr) j = (j & 255) * 256 + (j >> 8);   // read W[k][n] for out index (n,k)
  out[i] = flags[0] ? f2bf(((const float*)src)[j]) : ((const ushort*)src)[j];
}

// Exclusive scan -> CSR row_ptr, fused with dinv = rsqrt(cnt+1).
__global__ __launch_bounds__(1024) void scan_kernel(const int* cnt0, const int* cnt1,
                                                    int* rp0, int* rp1,
                                                    float* dinv0, float* dinv1) {
  const int* cnt = blockIdx.x ? cnt1 : cnt0;
  int* rp = blockIdx.x ? rp1 : rp0;
  float* dinv = blockIdx.x ? dinv1 : dinv0;
  __shared__ int sd[1024];
  int tid = threadIdx.x;
  int base = tid * 20;
  int pref[20];
  int run = 0;
#pragma unroll
  for (int k = 0; k < 20; k++) {
    int i = base + k;
    int c = (i < N_NODES) ? cnt[i] : 0;
    if (i < N_NODES) dinv[i] = rsqrtf((float)c + 1.0f);
    run += c;
    pref[k] = run;
  }
  sd[tid] = run;
  __syncthreads();
  for (int off = 1; off < 1024; off <<= 1) {
    int v = (tid >= off) ? sd[tid - off] : 0;
    __syncthreads();
    sd[tid] += v;
    __syncthreads();
  }
  int offset = sd[tid] - run;
  if (tid == 0) rp[0] = 0;
#pragma unroll
  for (int k = 0; k < 20; k++) {
    int i = base + k;
    if (i < N_NODES) rp[i + 1] = offset + pref[k];
  }
}

// Fill CSR using precomputed rank (no slot atomic). Edge record packed to
// 4 B: low16 = src (<20000 fits), high16 = bf16(coef) -- halves fill's
// scattered line writes AND agg's edge-stream bytes (r8 post-mortem).
// Plus t[src] += dinv[dst] (feeds layer-3 shortcut c_j = dinv_j*(t_j+dinv_j)).
__global__ void fill_kernel(const int* ei0, const int* ei1,
                            const float* dinv0, const float* dinv1,
                            const int* rp0, const int* rp1,
                            const int* rank0, const int* rank1,
                            unsigned int* eg0, unsigned int* eg1,
                            float* t0, float* t1) {
  int e = blockIdx.x * blockDim.x + threadIdx.x;
  if (e >= N_EDGES) return;
  int b = blockIdx.y;
  const int* ei = b ? ei1 : ei0;
  const float* dinv = b ? dinv1 : dinv0;
  const int* rp = b ? rp1 : rp0;
  const int* rank = b ? rank1 : rank0;
  unsigned int* eg = b ? eg1 : eg0;
  float* t = b ? t1 : t0;
  int src = ei[e], dst = ei[N_EDGES + e];
  int slot = rp[dst] + rank[e];
  float dd = dinv[dst];
  eg[slot] = (unsigned int)src | ((unsigned int)f2bf(dinv[src] * dd) << 16);
  atomicAdd(&t[src], dd);
}

// C[M,256] = A[M,256] @ W[256,256] with W given TRANSPOSED (Wt[n][k]).
// Block 256 thr = 4 waves; 64x64 tile; BK=32; 16x16x32 bf16 MFMA.
__global__ __launch_bounds__(256) void gemm_kernel(
    const ushort* __restrict__ A0, const ushort* __restrict__ A1,
    const ushort* __restrict__ Wt,
    ushort* __restrict__ C0, ushort* __restrict__ C1) {
  const ushort* A = blockIdx.z ? A1 : A0;
  ushort* C = blockIdx.z ? C1 : C0;
  int m0 = blockIdx.x * 64;
  int n0 = blockIdx.y * 64;
  __shared__ ushort As[64][40];   // row stride 80 B (not pow2 -> <=2-way, free)
  __shared__ ushort Bs[64][40];   // Bs[n][k] = Wt[(n0+n)*256 + k0+k]
  int tid = threadIdx.x;
  int wave = tid >> 6, lane = tid & 63;
  int quad = lane >> 4, r16 = lane & 15;
  f32x4 acc0 = {0.f, 0.f, 0.f, 0.f}, acc1 = acc0, acc2 = acc0, acc3 = acc0;
  int l_row = tid >> 2;           // 0..63
  int l_off = (tid & 3) * 8;      // 0,8,16,24
  for (int k0 = 0; k0 < 256; k0 += 32) {
    int gr = m0 + l_row;
    int4 va = {0, 0, 0, 0};
    if (gr < N_NODES) va = *(const int4*)(A + gr * 256 + k0 + l_off);
    *(int4*)&As[l_row][l_off] = va;
    int4 vb = *(const int4*)(Wt + (n0 + l_row) * 256 + k0 + l_off);
    *(int4*)&Bs[l_row][l_off] = vb;
    __syncthreads();
    bf16x8 a  = *(const bf16x8*)&As[wave * 16 + r16][quad * 8];
    bf16x8 b0 = *(const bf16x8*)&Bs[r16][quad * 8];
    bf16x8 b1 = *(const bf16x8*)&Bs[16 + r16][quad * 8];
    bf16x8 b2 = *(const bf16x8*)&Bs[32 + r16][quad * 8];
    bf16x8 b3 = *(const bf16x8*)&Bs[48 + r16][quad * 8];
    acc0 = __builtin_amdgcn_mfma_f32_16x16x32_bf16(a, b0, acc0, 0, 0, 0);
    acc1 = __builtin_amdgcn_mfma_f32_16x16x32_bf16(a, b1, acc1, 0, 0, 0);
    acc2 = __builtin_amdgcn_mfma_f32_16x16x32_bf16(a, b2, acc2, 0, 0, 0);
    acc3 = __builtin_amdgcn_mfma_f32_16x16x32_bf16(a, b3, acc3, 0, 0, 0);
    __syncthreads();
  }
  int orow = m0 + wave * 16 + quad * 4;
#pragma unroll
  for (int r = 0; r < 4; r++) {
    int gr = orow + r;
    if (gr < N_NODES) {
      ushort* cp = C + gr * 256 + n0 + r16;
      cp[0]  = f2bf(acc0[r]);
      cp[16] = f2bf(acc1[r]);
      cp[32] = f2bf(acc2[r]);
      cp[48] = f2bf(acc3[r]);
    }
  }
}

// H[i] = relu( dinv_i^2*XW[i] + sum_e coef_e*XW[src_e] + bias ).
// r9 design: wave = 2 INDEPENDENT 32-lane halves, one node each; lane owns 8
// features (us8 b128) -> half covers the full 256-col row. No cross-lane
// merge at all (r6 paid ~24 shfl ops/node); divergence waste only
// E[max2 Po(16)]/16 ~ 1.2x (r8's max8 was 1.6x). x4 unroll + dual
// accumulators: 8 full rows (64 lines) in flight per wave -- the MLP that
// made r6 fast (r8 post-mortem: line-level parallelism >> cache-slice
// residency for random gathers). Edge records 4 B packed.
__global__ __launch_bounds__(256) void agg_kernel(
    const ushort* __restrict__ XW0, const ushort* __restrict__ XW1,
    const float* __restrict__ dinv0, const float* __restrict__ dinv1,
    const int* __restrict__ rp0, const int* __restrict__ rp1,
    const unsigned int* __restrict__ eg0, const unsigned int* __restrict__ eg1,
    const ushort* __restrict__ bias,
    ushort* __restrict__ H0, ushort* __restrict__ H1) {
  int b = blockIdx.y;
  const ushort* XW = b ? XW1 : XW0;
  const float* dinv = b ? dinv1 : dinv0;
  const int* rp = b ? rp1 : rp0;
  const unsigned int* eg = b ? eg1 : eg0;
  ushort* H = b ? H1 : H0;
  int wave = threadIdx.x >> 6, lane = threadIdx.x & 63;
  int half = lane >> 5;
  int fl = (lane & 31) * 8;               // 8 features per lane = full row/half
  int i = blockIdx.x * 8 + wave * 2 + half;   // 2500*8 = 20000 exact
  float di = dinv[i];
  float selfw = di * di;
  us8 v = *(const us8*)(XW + i * 256 + fl);
  float acc[8], acc2[8];
#pragma unroll
  for (int k = 0; k < 8; k++) { acc[k] = selfw * bf2f(v[k]); acc2[k] = 0.f; }
  int e = rp[i], eend = rp[i + 1];
  for (; e + 4 <= eend; e += 4) {
    unsigned int p0 = eg[e], p1 = eg[e + 1], p2 = eg[e + 2], p3 = eg[e + 3];
    us8 r0 = *(const us8*)(XW + (p0 & 0xFFFFu) * 256 + fl);
    us8 r1 = *(const us8*)(XW + (p1 & 0xFFFFu) * 256 + fl);
    us8 r2 = *(const us8*)(XW + (p2 & 0xFFFFu) * 256 + fl);
    us8 r3 = *(const us8*)(XW + (p3 & 0xFFFFu) * 256 + fl);
    float w0 = bf2f((ushort)(p0 >> 16)), w1 = bf2f((ushort)(p1 >> 16));
    float w2 = bf2f((ushort)(p2 >> 16)), w3 = bf2f((ushort)(p3 >> 16));
#pragma unroll
    for (int k = 0; k < 8; k++) {
      acc[k]  += w0 * bf2f(r0[k]);
      acc2[k] += w1 * bf2f(r1[k]);
      acc[k]  += w2 * bf2f(r2[k]);
      acc2[k] += w3 * bf2f(r3[k]);
    }
  }
  for (; e < eend; e++) {
    unsigned int pp = eg[e];
    us8 r = *(const us8*)(XW + (pp & 0xFFFFu) * 256 + fl);
    float w = bf2f((ushort)(pp >> 16));
#pragma unroll
    for (int k = 0; k < 8; k++) acc[k] += w * bf2f(r[k]);
  }
  us8 bb = *(const us8*)(bias + fl);
  us8 o;
#pragma unroll
  for (int k = 0; k < 8; k++)
    o[k] = f2bf(fmaxf(acc[k] + acc2[k] + bf2f(bb[k]), 0.f));
  *(us8*)(H + i * 256 + fl) = o;          // half writes its node's full row
}

// Partial column sums: wave w of block handles rows j = (blk*4+w) + 256*k.
__global__ __launch_bounds__(256) void colsum_kernel(
    const ushort* __restrict__ H0, const ushort* __restrict__ H1,
    const float* __restrict__ dinv0, const float* __restrict__ dinv1,
    const float* __restrict__ t0, const float* __restrict__ t1,
    float* __restrict__ P) {
  int b = blockIdx.y;
  const ushort* H = b ? H1 : H0;
  const float* dinv = b ? dinv1 : dinv0;
  const float* t = b ? t1 : t0;
  int wave = threadIdx.x >> 6, lane = threadIdx.x & 63;
  int wid = blockIdx.x * 4 + wave;        // 0..255
  int f4 = lane * 4;
  float a0 = 0.f, a1 = 0.f, a2 = 0.f, a3 = 0.f;
  for (int j = wid; j < N_NODES; j += 256) {
    float dj = dinv[j];
    float c = dj * (t[j] + dj);
    ushort4 u = *(const ushort4*)(H + j * 256 + f4);
    a0 += c * bf2f(u.x); a1 += c * bf2f(u.y);
    a2 += c * bf2f(u.z); a3 += c * bf2f(u.w);
  }
  __shared__ float part[4][256];
  part[wave][f4 + 0] = a0; part[wave][f4 + 1] = a1;
  part[wave][f4 + 2] = a2; part[wave][f4 + 3] = a3;
  __syncthreads();
  int f = threadIdx.x;
  float ssum = part[0][f] + part[1][f] + part[2][f] + part[3][f];
  P[(b * 64 + blockIdx.x) * 256 + f] = ssum;
}

// s = reduce partials; pooled = ((s0+s1)@W3)/(2N)+b3 ; out = pooled@Wl + bl
__global__ __launch_bounds__(256) void final_kernel(
    const float* __restrict__ P,
    const ushort* __restrict__ W3, const ushort* __restrict__ b3,
    const ushort* __restrict__ Wl, const ushort* __restrict__ bl,
    void* __restrict__ out, const int* __restrict__ flags) {
  __shared__ float v[256];
  __shared__ float pooled[256];
  int t = threadIdx.x;
  float acc0 = 0.f, acc1 = 0.f;
  for (int b = 0; b < 64; b++) {
    acc0 += P[b * 256 + t];
    acc1 += P[(64 + b) * 256 + t];
  }
  v[t] = acc0 + acc1;
  __syncthreads();
  float acc = 0.f;
  for (int f = 0; f < 256; f++) acc += v[f] * bf2f(W3[f * 256 + t]);
  pooled[t] = acc * (1.0f / (2.0f * N_NODES)) + bf2f(b3[t]);
  __syncthreads();
  if (t < 5) {
    float o = bf2f(bl[t]);
    for (int h = 0; h < 256; h++) o += pooled[h] * bf2f(Wl[h * 5 + t]);
    if (flags[0]) ((float*)out)[t] = o;
    else ((ushort*)out)[t] = f2bf(o);
  }
}

extern "C" void kernel_launch(void* const* d_in, const int* in_sizes, int n_in,
                              void* d_out, int out_size, void* d_ws, size_t ws_size,
                              hipStream_t stream) {
  const void* x1 = d_in[0];
  const void* ei1 = d_in[1];
  const void* x2 = d_in[2];
  const void* ei2 = d_in[3];
  const void* W1 = d_in[4];
  const void* b1 = d_in[5];
  const void* W2 = d_in[6];
  const void* b2 = d_in[7];
  const void* W3 = d_in[8];
  const void* b3 = d_in[9];
  const void* Wl = d_in[10];
  const void* bl = d_in[11];

  char* p = (char*)d_ws;
  auto alloc = [&](size_t bytes) {
    char* r = p;
    p += (bytes + 255) & ~size_t(255);
    return r;
  };
  int* flags   = (int*)alloc(256);
  float* dinv0 = (float*)alloc(N_NODES * 4);
  float* dinv1 = (float*)alloc(N_NODES * 4);
  float* t0    = (float*)alloc(N_NODES * 4);
  float* t1    = (float*)alloc(N_NODES * 4);
  int* cnt0    = (int*)alloc(N_NODES * 4);
  int* cnt1    = (int*)alloc(N_NODES * 4);
  int* rp0     = (int*)alloc((N_NODES + 1) * 4);
  int* rp1     = (int*)alloc((N_NODES + 1) * 4);
  unsigned int* eg0 = (unsigned int*)alloc((size_t)N_EDGES * 4);
  unsigned int* eg1 = (unsigned int*)alloc((size_t)N_EDGES * 4);
  float* Pp    = (float*)alloc(2 * 64 * 256 * 4);
  ushort* wbuf = (ushort*)alloc(198661 * 2);
  ushort* xw0  = (ushort*)alloc((size_t)N_NODES * HID * 2);
  ushort* xw1  = (ushort*)alloc((size_t)N_NODES * HID * 2);
  ushort* xc0  = (ushort*)alloc((size_t)N_NODES * HID * 2);
  ushort* xc1  = (ushort*)alloc((size_t)N_NODES * HID * 2);
  // Lifetime aliasing: ei32+rank live only until fill_kernel; xw0 is first
  // written by gemm1 (after fill). 2*2.56 + 2*1.28 = 7.7MB <= 10.24MB.
  int* ei32_0 = (int*)xw0;
  int* ei32_1 = ei32_0 + 2 * N_EDGES;
  int* rank0  = ei32_1 + 2 * N_EDGES;
  int* rank1  = rank0 + N_EDGES;
  // xc dead after gemm1 reads it; h first written by agg1 (after gemm1).
  ushort* h0 = xc0;
  ushort* h1 = xc1;

  ushort* Wc1 = wbuf + 0;        // transposed
  ushort* Wc2 = wbuf + 65536;    // transposed
  ushort* Wc3 = wbuf + 131072;
  ushort* Wlc = wbuf + 196608;
  ushort* bc1 = wbuf + 197888;
  ushort* bc2 = wbuf + 198144;
  ushort* bc3 = wbuf + 198400;
  ushort* blc = wbuf + 198656;

  // --- init+detect fused, canonicalization, graph prep ---
  init_detect_kernel<<<(N_NODES + 255) / 256 + 1, 256, 0, stream>>>(
      cnt0, cnt1, t0, t1, x1, ei1, flags);
  cvt_ei_count_kernel<<<dim3((2 * N_EDGES + 255) / 256, 2), 256, 0, stream>>>(
      ei1, ei2, ei32_0, ei32_1, cnt0, cnt1, rank0, rank1, flags);
  cvt_x_kernel<<<dim3(N_NODES * HID / 1024, 2), 256, 0, stream>>>(
      x1, x2, xc0, xc1, flags);
  cvt_w_kernel<<<(198661 + 255) / 256, 256, 0, stream>>>(
      W1, W2, W3, Wl, b1, b2, b3, bl, wbuf, flags);
  scan_kernel<<<2, 1024, 0, stream>>>(cnt0, cnt1, rp0, rp1, dinv0, dinv1);
  fill_kernel<<<dim3((N_EDGES + 255) / 256, 2), 256, 0, stream>>>(
      ei32_0, ei32_1, dinv0, dinv1, rp0, rp1, rank0, rank1, eg0, eg1, t0, t1);

  // Layer 1: xw = x @ W1 ; h = relu(agg(xw) + b1)
  gemm_kernel<<<dim3(313, 4, 2), 256, 0, stream>>>(xc0, xc1, Wc1, xw0, xw1);
  agg_kernel<<<dim3(2500, 2), 256, 0, stream>>>(
      xw0, xw1, dinv0, dinv1, rp0, rp1, eg0, eg1, bc1, h0, h1);

  // Layer 2: xw = h @ W2 ; h = relu(agg(xw) + b2)
  gemm_kernel<<<dim3(313, 4, 2), 256, 0, stream>>>(h0, h1, Wc2, xw0, xw1);
  agg_kernel<<<dim3(2500, 2), 256, 0, stream>>>(
      xw0, xw1, dinv0, dinv1, rp0, rp1, eg0, eg1, bc2, h0, h1);

  // Layer 3 + pool collapsed: s = sum_j c_j h2_j ; out = ((s0+s1)W3/(2N)+b3)@Wl+bl
  colsum_kernel<<<dim3(64, 2), 256, 0, stream>>>(h0, h1, dinv0, dinv1, t0, t1, Pp);
  final_kernel<<<1, 256, 0, stream>>>(Pp, Wc3, bc3, Wlc, blc, d_out, flags);
}